// Round 5
// baseline (217.270 us; speedup 1.0000x reference)
//
#include <hip/hip_runtime.h>
#include <hip/hip_bf16.h>

typedef unsigned short u16;
typedef unsigned int u32;
typedef __attribute__((ext_vector_type(8))) short short8;   // 8 bf16 (4 VGPRs)
typedef __attribute__((ext_vector_type(4))) float f32x4;    // MFMA accumulator
typedef __attribute__((ext_vector_type(4))) u16 u16x4;

static constexpr int Bb = 512, Tt = 256, Cc = 768, Hh = 64;

__device__ __forceinline__ u16 f2bf(float f) {
    __hip_bfloat16 h = __float2bfloat16(f);   // RNE
    union { __hip_bfloat16 h; u16 u; } v; v.h = h;
    return v.u;
}

__device__ __forceinline__ void gll16(const u16* g, u16* l) {
    __builtin_amdgcn_global_load_lds(
        (const __attribute__((address_space(1))) u32*)g,
        (__attribute__((address_space(3))) u32*)l, 16, 0, 0);
}

// ---------------------------------------------------------------------------
// Kernel 0: arrange Wq|Wk|Wv into k-chunked, PRE-SWIZZLED bf16 layout so the
// proj kernel can stage each 24 KB chunk with linear global_load_lds and read
// B-fragments at swizzled addresses (byte ^= (n&7)<<4) conflict-free.
// ---------------------------------------------------------------------------
__global__ void wt_kernel(const float* __restrict__ Wq, const float* __restrict__ Wk,
                          const float* __restrict__ Wv, u16* __restrict__ Wt) {
    int idx = blockIdx.x * 256 + threadIdx.x;          // 192*768
    int n = idx / Cc, k = idx % Cc;
    const float* W = (n < 64) ? Wq : (n < 128) ? Wk : Wv;
    float val = W[k * Hh + (n & 63)];
    int kc = k >> 6, kl = k & 63;
    int lb = (n * 128 + kl * 2) ^ ((n & 7) << 4);
    Wt[kc * 12288 + (lb >> 1)] = f2bf(val);
}

// ---------------------------------------------------------------------------
// Kernel 1: fused QKV projection GEMM, counted-vmcnt pipeline (T3/T4), depth-2
// x prefetch, raw s_barrier, vmcnt never drained to 0 in the main loop.
// NO sched_barrier pins (round-4 lesson / m141): compiler schedules freely
// within phases; asm "memory" waitcnts fence memory-op order only.
// Ledger per chunk i (steady entry {W_i:3, X_{i+1}:4} = 7 outstanding):
//   WTSTAGE(i+1)+3 -> 10 | XLOAD(i+2)+4 -> 14 | vmcnt(11) drains W_i |
//   COMPUTE(i) | vmcnt(7) drains X_{i+1} | XWRITE | lgkm0 + s_barrier -> 7.
// Epilogue: LDS-bounce -> FRAGMENT-MAJOR q/k/v (1 KB coalesced frag blocks).
// ---------------------------------------------------------------------------
__global__ __launch_bounds__(512, 4) void proj_kernel(
        const float* __restrict__ x, const u16* __restrict__ Wt,
        u16* __restrict__ qf, u16* __restrict__ kf, u16* __restrict__ vf) {
    __shared__ u16 smem[40960];   // loop: xs[2]=smem+{0,8192}, ws[2]=smem+16384+{0,12288}
                                  // epilogue: qk=smem[0..16384), vt=smem+16384
    const int tid = threadIdx.x;
    const int wave = tid >> 6, l = tid & 63;
    const int lrow = l & 15, lgrp = l >> 4;
    const int wr = wave >> 2, wc = wave & 3;
    const size_t m0 = (size_t)blockIdx.x * 128;
    const int cswz = (lrow & 7) << 4;

    const int xsr = tid >> 4, xsc = tid & 15;
    const float* xg = x + (m0 + xsr) * Cc + xsc * 4;

    float4 xrA[4], xrB[4];
    f32x4 acc[4][3];
#pragma unroll
    for (int i = 0; i < 4; ++i)
#pragma unroll
        for (int j = 0; j < 3; ++j) acc[i][j] = (f32x4)0.f;

#define XLOAD(kc_, R_)                                                         \
    _Pragma("unroll")                                                          \
    for (int j = 0; j < 4; ++j)                                                \
        R_[j] = *(const float4*)(xg + (size_t)j * 32 * Cc + (kc_) * 64);

#define XWRITE(R_, nb_)                                                        \
    {                                                                          \
        u16* xb_ = smem + (nb_) * 8192;                                        \
        _Pragma("unroll")                                                      \
        for (int j = 0; j < 4; ++j) {                                          \
            int row = j * 32 + xsr;                                            \
            u16x4 pk;                                                          \
            pk[0] = f2bf(R_[j].x); pk[1] = f2bf(R_[j].y);                      \
            pk[2] = f2bf(R_[j].z); pk[3] = f2bf(R_[j].w);                      \
            int off = (row * 128 + xsc * 8) ^ ((row & 7) << 4);                \
            *(u16x4*)((char*)xb_ + off) = pk;                                  \
        }                                                                      \
    }

#define WTSTAGE(kc_, nb_)                                                      \
    {                                                                          \
        u16* wl_ = smem + 16384 + (nb_) * 12288;                               \
        _Pragma("unroll")                                                      \
        for (int i = 0; i < 3; ++i)                                            \
            gll16(Wt + (size_t)(kc_) * 12288 + i * 4096 + wave * 512 + l * 8,  \
                  wl_ + i * 4096 + wave * 512);                                \
    }

#define COMPUTE(cur_)                                                          \
    {                                                                          \
        const char* xb = (const char*)(smem + (cur_) * 8192);                  \
        const char* wb = (const char*)(smem + 16384 + (cur_) * 12288);         \
        _Pragma("unroll")                                                      \
        for (int ksub = 0; ksub < 2; ++ksub) {                                 \
            short8 af[4], bfr[3];                                              \
            _Pragma("unroll")                                                  \
            for (int mrep = 0; mrep < 4; ++mrep)                               \
                af[mrep] = *(const short8*)(xb +                               \
                    (((wr * 64 + mrep * 16 + lrow) * 128 + ksub * 64 + lgrp * 16) ^ cswz)); \
            _Pragma("unroll")                                                  \
            for (int ntl = 0; ntl < 3; ++ntl)                                  \
                bfr[ntl] = *(const short8*)(wb +                               \
                    (((wc * 48 + ntl * 16 + lrow) * 128 + ksub * 64 + lgrp * 16) ^ cswz)); \
            _Pragma("unroll")                                                  \
            for (int mrep = 0; mrep < 4; ++mrep)                               \
                _Pragma("unroll")                                              \
                for (int ntl = 0; ntl < 3; ++ntl)                              \
                    acc[mrep][ntl] = __builtin_amdgcn_mfma_f32_16x16x32_bf16(  \
                        af[mrep], bfr[ntl], acc[mrep][ntl], 0, 0, 0);          \
        }                                                                      \
    }

#define STEP_MAIN(i_, CUR_, RL_, RW_)                                          \
    WTSTAGE((i_) + 1, 1 - (CUR_));                                             \
    XLOAD((i_) + 2, RL_);                                                      \
    asm volatile("s_waitcnt vmcnt(11)" ::: "memory");                          \
    COMPUTE(CUR_);                                                             \
    asm volatile("s_waitcnt vmcnt(7)" ::: "memory");                           \
    XWRITE(RW_, 1 - (CUR_));                                                   \
    asm volatile("s_waitcnt lgkmcnt(0)" ::: "memory");                         \
    __builtin_amdgcn_s_barrier();

    // ---- Prologue: establish steady state {W_0, X_1} in flight ----
    XLOAD(0, xrA);
    WTSTAGE(0, 0);
    XLOAD(1, xrB);
    asm volatile("s_waitcnt vmcnt(7)" ::: "memory");   // X_0 done
    XWRITE(xrA, 0);
    asm volatile("s_waitcnt lgkmcnt(0)" ::: "memory");
    __builtin_amdgcn_s_barrier();

    // ---- Main loop: chunks 0..9 (uniform), unrolled x2 for static reg sets
    for (int ii = 0; ii < 5; ++ii) {
        const int ie = ii * 2;
        STEP_MAIN(ie, 0, xrA, xrB);
        STEP_MAIN(ie + 1, 1, xrB, xrA);
    }

    // ---- Tail chunk 10 ----
    WTSTAGE(11, 1);
    asm volatile("s_waitcnt vmcnt(7)" ::: "memory");   // W_10 done
    COMPUTE(0);
    asm volatile("s_waitcnt vmcnt(3)" ::: "memory");   // X_11 done
    XWRITE(xrB, 1);
    asm volatile("s_waitcnt lgkmcnt(0)" ::: "memory");
    __builtin_amdgcn_s_barrier();

    // ---- Tail chunk 11 ----
    asm volatile("s_waitcnt vmcnt(0)" ::: "memory");   // W_11 done
    COMPUTE(1);
    __syncthreads();
#undef STEP_MAIN
#undef COMPUTE
#undef WTSTAGE
#undef XWRITE
#undef XLOAD

    // ---- Epilogue: scatter acc -> swizzled LDS tiles ----
    u16* qk = smem;            // [128 s][128 n] bf16, 256 B rows, XOR-swizzled
    u16* vt = smem + 16384;    // [64 h][128 s] bf16, 256 B rows, XOR-swizzled
#pragma unroll
    for (int mrep = 0; mrep < 4; ++mrep) {
        int sl = wr * 64 + mrep * 16 + lgrp * 4;       // local row (s)
#pragma unroll
        for (int ntl = 0; ntl < 3; ++ntl) {
            int n = wc * 48 + ntl * 16 + lrow;
            f32x4 a = acc[mrep][ntl];
            if (n < 128) {                              // q | k
#pragma unroll
                for (int r = 0; r < 4; ++r) {
                    int row = sl + r;
                    int off = (row * 256 + n * 2) ^ ((row & 7) << 4);
                    *(u16*)((char*)qk + off) = f2bf(a[r]);
                }
            } else {                                    // v (transposed)
                int h = n - 128;
                u16x4 pk;
                pk[0] = f2bf(a[0]); pk[1] = f2bf(a[1]);
                pk[2] = f2bf(a[2]); pk[3] = f2bf(a[3]);
                int off = (h * 256 + sl * 2) ^ ((h & 7) << 4);
                *(u16x4*)((char*)vt + off) = pk;
            }
        }
    }
    __syncthreads();

    // ---- Gather MFMA fragments, store fragment-major (coalesced 1 KB) ----
    const size_t rt0 = m0 >> 4;                 // first 16-row tile index
    const int bidx = (int)(m0 >> 8);            // batch
    const int sb5 = (int)((m0 & 255) >> 5);     // s-chunk base (0 or 4)
#pragma unroll
    for (int it = 0; it < 6; ++it) {
        int f = it * 8 + wave;                  // 48 fragments total
        const char* src;
        u16* dst;
        if (f < 16) {                           // Q frags
            int t = f >> 1, c = f & 1;
            int row = t * 16 + lrow;
            src = (const char*)qk + ((row * 256 + (c * 32 + lgrp * 8) * 2) ^ ((row & 7) << 4));
            dst = qf + ((rt0 + t) * 2 + c) * 512 + l * 8;
        } else if (f < 32) {                    // K frags
            int g = f - 16, t = g >> 1, c = g & 1;
            int row = t * 16 + lrow;
            src = (const char*)qk + ((row * 256 + 128 + (c * 32 + lgrp * 8) * 2) ^ ((row & 7) << 4));
            dst = kf + ((rt0 + t) * 2 + c) * 512 + l * 8;
        } else {                                // V frags
            int g = f - 32, ks = g >> 2, ht = g & 3;
            int row = ht * 16 + lrow;
            src = (const char*)vt + ((row * 256 + (ks * 32 + lgrp * 8) * 2) ^ ((row & 7) << 4));
            dst = vf + (size_t)bidx * 16384 + ((sb5 + ks) * 4 + ht) * 512 + l * 8;
        }
        short8 v = *(const short8*)src;
        *(short8*)dst = v;
    }
}

// ---------------------------------------------------------------------------
// Kernel 2: causal attention; ALL fragment loads are coalesced 1 KB wave-loads
// from the fragment-major qf/kf/vf buffers (L2/L3-resident per batch).
// ---------------------------------------------------------------------------
__global__ __launch_bounds__(256) void attn_kernel(
        const u16* __restrict__ qf, const u16* __restrict__ kf,
        const u16* __restrict__ vf, const int* __restrict__ pad,
        float* __restrict__ out) {
    __shared__ u16 Plds[4][16][264];

    const int wave = threadIdx.x >> 6, l = threadIdx.x & 63;
    const int lrow = l & 15, lgrp = l >> 4;
    const int b = blockIdx.x >> 2;
    const int i0 = (blockIdx.x & 3) * 64 + wave * 16;

    const u16* qb = qf + (size_t)(b * 16 + (i0 >> 4)) * 1024 + l * 8;
    short8 q0 = *(const short8*)qb;
    short8 q1 = *(const short8*)(qb + 512);

    f32x4 sreg[16];
    const u16* kb = kf + (size_t)b * 16384 + l * 8;
#pragma unroll
    for (int t = 0; t < 16; ++t) {
        short8 k0 = *(const short8*)(kb + t * 1024);
        short8 k1 = *(const short8*)(kb + t * 1024 + 512);
        f32x4 s = (f32x4)0.f;
        s = __builtin_amdgcn_mfma_f32_16x16x32_bf16(q0, k0, s, 0, 0, 0);
        s = __builtin_amdgcn_mfma_f32_16x16x32_bf16(q1, k1, s, 0, 0, 0);
#pragma unroll
        for (int r = 0; r < 4; ++r) {
            int i = i0 + lgrp * 4 + r;      // query row
            int sidx = t * 16 + lrow;       // key index
            sreg[t][r] = (sidx <= i) ? s[r] * 0.125f : -1e30f;
        }
    }

    f32x4 mx = sreg[0];
#pragma unroll
    for (int t = 1; t < 16; ++t)
#pragma unroll
        for (int r = 0; r < 4; ++r) mx[r] = fmaxf(mx[r], sreg[t][r]);
#pragma unroll
    for (int m = 1; m <= 8; m <<= 1)
#pragma unroll
        for (int r = 0; r < 4; ++r) mx[r] = fmaxf(mx[r], __shfl_xor(mx[r], m, 64));

    f32x4 sm = (f32x4)0.f;
#pragma unroll
    for (int t = 0; t < 16; ++t)
#pragma unroll
        for (int r = 0; r < 4; ++r) {
            float p = __expf(sreg[t][r] - mx[r]);
            sreg[t][r] = p;
            sm[r] += p;
        }
#pragma unroll
    for (int m = 1; m <= 8; m <<= 1)
#pragma unroll
        for (int r = 0; r < 4; ++r) sm[r] += __shfl_xor(sm[r], m, 64);

#pragma unroll
    for (int t = 0; t < 16; ++t)
#pragma unroll
        for (int r = 0; r < 4; ++r)
            Plds[wave][lgrp * 4 + r][t * 16 + lrow] = f2bf(sreg[t][r]);

    f32x4 o[4];
#pragma unroll
    for (int ht = 0; ht < 4; ++ht) o[ht] = (f32x4)0.f;
    const u16* vb0 = vf + (size_t)b * 16384 + l * 8;
#pragma unroll
    for (int ks = 0; ks < 8; ++ks) {
        short8 pa = *(const short8*)(&Plds[wave][lrow][ks * 32 + lgrp * 8]);
#pragma unroll
        for (int ht = 0; ht < 4; ++ht) {
            short8 vbf = *(const short8*)(vb0 + (ks * 4 + ht) * 512);
            o[ht] = __builtin_amdgcn_mfma_f32_16x16x32_bf16(pa, vbf, o[ht], 0, 0, 0);
        }
    }

#pragma unroll
    for (int r = 0; r < 4; ++r) {
        int i = i0 + lgrp * 4 + r;
        int pv = pad[b * Tt + i];
        float inv = (pv != 0) ? (1.0f / sm[r]) : 0.0f;
#pragma unroll
        for (int ht = 0; ht < 4; ++ht)
            out[((size_t)b * Tt + i) * Hh + ht * 16 + lrow] = o[ht][r] * inv;
    }
}

// ---------------------------------------------------------------------------
extern "C" void kernel_launch(void* const* d_in, const int* in_sizes, int n_in,
                              void* d_out, int out_size, void* d_ws, size_t ws_size,
                              hipStream_t stream) {
    const float* x  = (const float*)d_in[0];
    const float* Wq = (const float*)d_in[1];
    const float* Wk = (const float*)d_in[2];
    const float* Wv = (const float*)d_in[3];
    const int* pad  = (const int*)d_in[4];
    float* out = (float*)d_out;

    // Workspace (u16 units): Wt 147456 | qf 8388608 | kf 8388608 | vf 8388608
    u16* Wt = (u16*)d_ws;
    u16* qf = Wt + 147456;
    u16* kf = qf + 8388608;
    u16* vf = kf + 8388608;

    wt_kernel<<<576, 256, 0, stream>>>(Wq, Wk, Wv, Wt);
    proj_kernel<<<(Bb * Tt) / 128, 512, 0, stream>>>(x, Wt, qf, kf, vf);
    attn_kernel<<<Bb * 4, 256, 0, stream>>>(qf, kf, vf, pad, out);
}

// Round 6
// 160.116 us; speedup vs baseline: 1.3570x; 1.3570x over previous
//
#include <hip/hip_runtime.h>
#include <hip/hip_bf16.h>

typedef unsigned short u16;
typedef unsigned int u32;
typedef __attribute__((ext_vector_type(8))) short short8;   // 8 bf16 (4 VGPRs)
typedef __attribute__((ext_vector_type(4))) float f32x4;    // MFMA accumulator
typedef __attribute__((ext_vector_type(4))) u16 u16x4;

static constexpr int Bb = 512, Tt = 256, Cc = 768, Hh = 64;

__device__ __forceinline__ u16 f2bf(float f) {
    __hip_bfloat16 h = __float2bfloat16(f);   // RNE
    union { __hip_bfloat16 h; u16 u; } v; v.h = h;
    return v.u;
}

// ---------------------------------------------------------------------------
// Kernel 0: arrange Wq|Wk|Wv FRAGMENT-MAJOR: for chunk kc, ksub, wave-col wc,
// tile ntl, the 64-lane MFMA B-fragment is one contiguous 1 KB block:
//   frag id = (kc*2+ksub)*12 + wc*3 + ntl;  lane l holds n = base+(l&15),
//   k = kc*64+ksub*32+(l>>4)*8 + e.  proj loads each frag as ONE coalesced
//   wave-load from L2 — no LDS staging for W at all.
// ---------------------------------------------------------------------------
__global__ void wt_kernel(const float* __restrict__ Wq, const float* __restrict__ Wk,
                          const float* __restrict__ Wv, u16* __restrict__ Wf) {
    int idx = blockIdx.x * 256 + threadIdx.x;          // 192*768
    int n = idx / Cc, k = idx % Cc;
    const float* W = (n < 64) ? Wq : (n < 128) ? Wk : Wv;
    float val = W[k * Hh + (n & 63)];
    int wc = n / 48, ntl = (n % 48) / 16, fr = n & 15;
    int kc = k >> 6, ksub = (k >> 5) & 1, fk = k & 31;
    int fid = (kc * 2 + ksub) * 12 + wc * 3 + ntl;
    Wf[fid * 512 + (fr + (fk >> 3) * 16) * 8 + (fk & 7)] = f2bf(val);
}

// ---------------------------------------------------------------------------
// Kernel 1: fused QKV projection GEMM (round-3 loop structure, compiler-
// scheduled).  Block = 512 thr (8 waves as 2x4), tile 128 x 192, K_STEP 64.
// x: reg-staged f32->bf16 into double-buffered swizzled LDS (only barrier-
// protected resource).  W: per-chunk 6 coalesced 1 KB fragment loads from L2.
// Epilogue: LDS-bounce -> FRAGMENT-MAJOR q/k/v (1 KB coalesced frag blocks).
// ---------------------------------------------------------------------------
__global__ __launch_bounds__(512, 4) void proj_kernel(
        const float* __restrict__ x, const u16* __restrict__ Wf,
        u16* __restrict__ qf, u16* __restrict__ kf, u16* __restrict__ vf) {
    __shared__ u16 smem[24576];   // loop: xs[2] = smem+{0,8192} (32 KB)
                                  // epilogue: qk=smem[0..16384), vt=smem+16384
    const int tid = threadIdx.x;
    const int wave = tid >> 6, l = tid & 63;
    const int lrow = l & 15, lgrp = l >> 4;
    const int wr = wave >> 2, wc = wave & 3;
    const size_t m0 = (size_t)blockIdx.x * 128;
    const int cswz = (lrow & 7) << 4;

    const int xsr = tid >> 4, xsc = tid & 15;
    const float* xg = x + (m0 + xsr) * Cc + xsc * 4;
    const u16* wfl = Wf + (size_t)(wc * 3) * 512 + l * 8;

    float4 xr[4];
    short8 breg[2][3];
    f32x4 acc[4][3];
#pragma unroll
    for (int i = 0; i < 4; ++i)
#pragma unroll
        for (int j = 0; j < 3; ++j) acc[i][j] = (f32x4)0.f;

#define XLOAD(kc_)                                                             \
    _Pragma("unroll")                                                          \
    for (int j = 0; j < 4; ++j)                                                \
        xr[j] = *(const float4*)(xg + (size_t)j * 32 * Cc + (kc_) * 64);

#define XWRITE(nb_)                                                            \
    {                                                                          \
        u16* xb_ = smem + (nb_) * 8192;                                        \
        _Pragma("unroll")                                                      \
        for (int j = 0; j < 4; ++j) {                                          \
            int row = j * 32 + xsr;                                            \
            u16x4 pk;                                                          \
            pk[0] = f2bf(xr[j].x); pk[1] = f2bf(xr[j].y);                      \
            pk[2] = f2bf(xr[j].z); pk[3] = f2bf(xr[j].w);                      \
            int off = (row * 128 + xsc * 8) ^ ((row & 7) << 4);                \
            *(u16x4*)((char*)xb_ + off) = pk;                                  \
        }                                                                      \
    }

#define BLOAD(kc_)                                                             \
    _Pragma("unroll")                                                          \
    for (int ksub = 0; ksub < 2; ++ksub)                                       \
        _Pragma("unroll")                                                      \
        for (int ntl = 0; ntl < 3; ++ntl)                                      \
            breg[ksub][ntl] = *(const short8*)(wfl +                           \
                (size_t)(((kc_) * 2 + ksub) * 12 + ntl) * 512);

    // Prologue
    XLOAD(0); XWRITE(0);
    __syncthreads();

    for (int kc = 0; kc < 12; ++kc) {
        const int cur = kc & 1, nxt = cur ^ 1;
        BLOAD(kc);
        if (kc < 11) { XLOAD(kc + 1); }

        const char* xb = (const char*)(smem + cur * 8192);
#pragma unroll
        for (int ksub = 0; ksub < 2; ++ksub) {
            short8 af[4];
#pragma unroll
            for (int mrep = 0; mrep < 4; ++mrep)
                af[mrep] = *(const short8*)(xb +
                    (((wr * 64 + mrep * 16 + lrow) * 128 + ksub * 64 + lgrp * 16) ^ cswz));
#pragma unroll
            for (int mrep = 0; mrep < 4; ++mrep)
#pragma unroll
                for (int ntl = 0; ntl < 3; ++ntl)
                    acc[mrep][ntl] = __builtin_amdgcn_mfma_f32_16x16x32_bf16(
                        af[mrep], breg[ksub][ntl], acc[mrep][ntl], 0, 0, 0);
        }
        if (kc < 11) { XWRITE(nxt); }
        __syncthreads();
    }
#undef XLOAD
#undef XWRITE
#undef BLOAD

    // ---- Epilogue: scatter acc -> swizzled LDS tiles ----
    u16* qk = smem;            // [128 s][128 n] bf16, 256 B rows, XOR-swizzled
    u16* vt = smem + 16384;    // [64 h][128 s] bf16, 256 B rows, XOR-swizzled
#pragma unroll
    for (int mrep = 0; mrep < 4; ++mrep) {
        int sl = wr * 64 + mrep * 16 + lgrp * 4;       // local row (s)
#pragma unroll
        for (int ntl = 0; ntl < 3; ++ntl) {
            int n = wc * 48 + ntl * 16 + lrow;
            f32x4 a = acc[mrep][ntl];
            if (n < 128) {                              // q | k
#pragma unroll
                for (int r = 0; r < 4; ++r) {
                    int row = sl + r;
                    int off = (row * 256 + n * 2) ^ ((row & 7) << 4);
                    *(u16*)((char*)qk + off) = f2bf(a[r]);
                }
            } else {                                    // v (transposed)
                int h = n - 128;
                u16x4 pk;
                pk[0] = f2bf(a[0]); pk[1] = f2bf(a[1]);
                pk[2] = f2bf(a[2]); pk[3] = f2bf(a[3]);
                int off = (h * 256 + sl * 2) ^ ((h & 7) << 4);
                *(u16x4*)((char*)vt + off) = pk;
            }
        }
    }
    __syncthreads();

    // ---- Gather MFMA fragments, store fragment-major (coalesced 1 KB) ----
    const size_t rt0 = m0 >> 4;                 // first 16-row tile index
    const int bidx = (int)(m0 >> 8);            // batch
    const int sb5 = (int)((m0 & 255) >> 5);     // s-chunk base (0 or 4)
#pragma unroll
    for (int it = 0; it < 6; ++it) {
        int f = it * 8 + wave;                  // 48 fragments total
        const char* src;
        u16* dst;
        if (f < 16) {                           // Q frags
            int t = f >> 1, c = f & 1;
            int row = t * 16 + lrow;
            src = (const char*)qk + ((row * 256 + (c * 32 + lgrp * 8) * 2) ^ ((row & 7) << 4));
            dst = qf + ((rt0 + t) * 2 + c) * 512 + l * 8;
        } else if (f < 32) {                    // K frags
            int g = f - 16, t = g >> 1, c = g & 1;
            int row = t * 16 + lrow;
            src = (const char*)qk + ((row * 256 + 128 + (c * 32 + lgrp * 8) * 2) ^ ((row & 7) << 4));
            dst = kf + ((rt0 + t) * 2 + c) * 512 + l * 8;
        } else {                                // V frags
            int g = f - 32, ks = g >> 2, ht = g & 3;
            int row = ht * 16 + lrow;
            src = (const char*)vt + ((row * 256 + (ks * 32 + lgrp * 8) * 2) ^ ((row & 7) << 4));
            dst = vf + (size_t)bidx * 16384 + ((sb5 + ks) * 4 + ht) * 512 + l * 8;
        }
        short8 v = *(const short8*)src;
        *(short8*)dst = v;
    }
}

// ---------------------------------------------------------------------------
// Kernel 2: causal attention; ALL fragment loads are coalesced 1 KB wave-loads
// from the fragment-major qf/kf/vf buffers (L2/L3-resident per batch).
// ---------------------------------------------------------------------------
__global__ __launch_bounds__(256) void attn_kernel(
        const u16* __restrict__ qf, const u16* __restrict__ kf,
        const u16* __restrict__ vf, const int* __restrict__ pad,
        float* __restrict__ out) {
    __shared__ u16 Plds[4][16][264];

    const int wave = threadIdx.x >> 6, l = threadIdx.x & 63;
    const int lrow = l & 15, lgrp = l >> 4;
    const int b = blockIdx.x >> 2;
    const int i0 = (blockIdx.x & 3) * 64 + wave * 16;

    const u16* qb = qf + (size_t)(b * 16 + (i0 >> 4)) * 1024 + l * 8;
    short8 q0 = *(const short8*)qb;
    short8 q1 = *(const short8*)(qb + 512);

    f32x4 sreg[16];
    const u16* kb = kf + (size_t)b * 16384 + l * 8;
#pragma unroll
    for (int t = 0; t < 16; ++t) {
        short8 k0 = *(const short8*)(kb + t * 1024);
        short8 k1 = *(const short8*)(kb + t * 1024 + 512);
        f32x4 s = (f32x4)0.f;
        s = __builtin_amdgcn_mfma_f32_16x16x32_bf16(q0, k0, s, 0, 0, 0);
        s = __builtin_amdgcn_mfma_f32_16x16x32_bf16(q1, k1, s, 0, 0, 0);
#pragma unroll
        for (int r = 0; r < 4; ++r) {
            int i = i0 + lgrp * 4 + r;      // query row
            int sidx = t * 16 + lrow;       // key index
            sreg[t][r] = (sidx <= i) ? s[r] * 0.125f : -1e30f;
        }
    }

    f32x4 mx = sreg[0];
#pragma unroll
    for (int t = 1; t < 16; ++t)
#pragma unroll
        for (int r = 0; r < 4; ++r) mx[r] = fmaxf(mx[r], sreg[t][r]);
#pragma unroll
    for (int m = 1; m <= 8; m <<= 1)
#pragma unroll
        for (int r = 0; r < 4; ++r) mx[r] = fmaxf(mx[r], __shfl_xor(mx[r], m, 64));

    f32x4 sm = (f32x4)0.f;
#pragma unroll
    for (int t = 0; t < 16; ++t)
#pragma unroll
        for (int r = 0; r < 4; ++r) {
            float p = __expf(sreg[t][r] - mx[r]);
            sreg[t][r] = p;
            sm[r] += p;
        }
#pragma unroll
    for (int m = 1; m <= 8; m <<= 1)
#pragma unroll
        for (int r = 0; r < 4; ++r) sm[r] += __shfl_xor(sm[r], m, 64);

#pragma unroll
    for (int t = 0; t < 16; ++t)
#pragma unroll
        for (int r = 0; r < 4; ++r)
            Plds[wave][lgrp * 4 + r][t * 16 + lrow] = f2bf(sreg[t][r]);

    f32x4 o[4];
#pragma unroll
    for (int ht = 0; ht < 4; ++ht) o[ht] = (f32x4)0.f;
    const u16* vb0 = vf + (size_t)b * 16384 + l * 8;
#pragma unroll
    for (int ks = 0; ks < 8; ++ks) {
        short8 pa = *(const short8*)(&Plds[wave][lrow][ks * 32 + lgrp * 8]);
#pragma unroll
        for (int ht = 0; ht < 4; ++ht) {
            short8 vbf = *(const short8*)(vb0 + (ks * 4 + ht) * 512);
            o[ht] = __builtin_amdgcn_mfma_f32_16x16x32_bf16(pa, vbf, o[ht], 0, 0, 0);
        }
    }

#pragma unroll
    for (int r = 0; r < 4; ++r) {
        int i = i0 + lgrp * 4 + r;
        int pv = pad[b * Tt + i];
        float inv = (pv != 0) ? (1.0f / sm[r]) : 0.0f;
#pragma unroll
        for (int ht = 0; ht < 4; ++ht)
            out[((size_t)b * Tt + i) * Hh + ht * 16 + lrow] = o[ht][r] * inv;
    }
}

// ---------------------------------------------------------------------------
extern "C" void kernel_launch(void* const* d_in, const int* in_sizes, int n_in,
                              void* d_out, int out_size, void* d_ws, size_t ws_size,
                              hipStream_t stream) {
    const float* x  = (const float*)d_in[0];
    const float* Wq = (const float*)d_in[1];
    const float* Wk = (const float*)d_in[2];
    const float* Wv = (const float*)d_in[3];
    const int* pad  = (const int*)d_in[4];
    float* out = (float*)d_out;

    // Workspace (u16 units): Wf 147456 | qf 8388608 | kf 8388608 | vf 8388608
    u16* Wf = (u16*)d_ws;
    u16* qf = Wf + 147456;
    u16* kf = qf + 8388608;
    u16* vf = kf + 8388608;

    wt_kernel<<<576, 256, 0, stream>>>(Wq, Wk, Wv, Wf);
    proj_kernel<<<(Bb * Tt) / 128, 512, 0, stream>>>(x, Wf, qf, kf, vf);
    attn_kernel<<<Bb * 4, 256, 0, stream>>>(qf, kf, vf, pad, out);
}

// Round 7
// 120.169 us; speedup vs baseline: 1.8080x; 1.3324x over previous
//
#include <hip/hip_runtime.h>
#include <hip/hip_bf16.h>

typedef unsigned short u16;
typedef unsigned int u32;
typedef __attribute__((ext_vector_type(8))) short short8;   // 8 bf16 (4 VGPRs)
typedef __attribute__((ext_vector_type(4))) float f32x4;    // MFMA accumulator
typedef __attribute__((ext_vector_type(4))) u16 u16x4;

static constexpr int Bb = 512, Tt = 256, Cc = 768, Hh = 64;

__device__ __forceinline__ u16 f2bf(float f) {
    __hip_bfloat16 h = __float2bfloat16(f);   // RNE
    union { __hip_bfloat16 h; u16 u; } v; v.h = h;
    return v.u;
}

__device__ __forceinline__ void gll16(const u16* g, u16* l) {
    __builtin_amdgcn_global_load_lds(
        (const __attribute__((address_space(1))) u32*)g,
        (__attribute__((address_space(3))) u32*)l, 16, 0, 0);
}

// ---------------------------------------------------------------------------
// Kernel 0: Wq|Wk|Wv -> per-K-chunk fragment-major image (the exact LDS image
// the fused kernel stages with linear global_load_lds):
//   chunk kc holds 24 frags of 1 KB: f = ksub*12 + nt; lane l of frag f gives
//   n = nt*16+(l&15), k = kc*64+ksub*32+(l>>4)*8+e.
// ---------------------------------------------------------------------------
__global__ void wt_kernel(const float* __restrict__ Wq, const float* __restrict__ Wk,
                          const float* __restrict__ Wv, u16* __restrict__ Wf) {
    int idx = blockIdx.x * 256 + threadIdx.x;          // 192*768
    int n = idx / Cc, k = idx % Cc;
    const float* W = (n < 64) ? Wq : (n < 128) ? Wk : Wv;
    float val = W[k * Hh + (n & 63)];
    int nt = n >> 4, fr = n & 15;
    int kc = k >> 6, ksub = (k >> 5) & 1, fk = k & 31;
    Wf[kc * 12288 + (ksub * 12 + nt) * 512 + (fr + ((fk >> 3) << 4)) * 8 + (fk & 7)] = f2bf(val);
}

// ---------------------------------------------------------------------------
// Fused kernel: one block per batch. 512 thr = 8 waves.
// Phase 1 (QKV GEMM): wave w owns query-row tiles {w, 15-w} (16 rows each,
//   balanced causal work). x reg-staged f32->bf16 into dbuf swizzled LDS
//   (round-3 structure); W chunk staged once to LDS via global_load_lds,
//   broadcast-read by all waves. acc[2][12] covers 32 rows x 192 cols.
// Epilogue: acc -> LDS: K tile [256][64], V^T [64][256], Q bounce [256][64];
//   read back Q as MFMA A-frags.
// Phase 2 (causal attention, no barriers): per m-tile: QK^T (skip masked
//   tiles), wave softmax, chunked P->LDS (per-wave dbuf), PV, write out.
// LDS map (bytes): phase1: XS dbuf [0,65536) | WS dbuf [65536,114688)
//                  phase2: KT [0,32768) | VT [32768,65536) | QB [65536,98304)
//                          | P [98304,118784)
// ---------------------------------------------------------------------------
__global__ __launch_bounds__(512, 2) void fused_kernel(
        const float* __restrict__ x, const u16* __restrict__ Wf,
        const int* __restrict__ pad, float* __restrict__ out) {
    __shared__ u16 smem[59392];   // 118784 B
    char* smB = (char*)smem;

    const int tid = threadIdx.x;
    const int w = tid >> 6, l = tid & 63;
    const int lrow = l & 15, lgrp = l >> 4;
    const int b = blockIdx.x;
    const int cswz = (lrow & 7) << 4;
    const int tt0 = w, tt1 = 15 - w;          // owned query-row tiles

    const float* xg = x + ((size_t)b * Tt + (tid >> 4)) * Cc + (tid & 15) * 4;

    float4 xr[8];
    f32x4 acc[2][12];
#pragma unroll
    for (int i = 0; i < 2; ++i)
#pragma unroll
        for (int j = 0; j < 12; ++j) acc[i][j] = (f32x4)0.f;

#define XLOAD(kc_)                                                             \
    _Pragma("unroll")                                                          \
    for (int j = 0; j < 8; ++j)                                                \
        xr[j] = *(const float4*)(xg + (size_t)j * 32 * Cc + (kc_) * 64);

#define XWRITE(nb_)                                                            \
    {                                                                          \
        char* xb_ = smB + (nb_) * 32768;                                       \
        _Pragma("unroll")                                                      \
        for (int j = 0; j < 8; ++j) {                                          \
            int row = j * 32 + (tid >> 4);                                     \
            u16x4 pk;                                                          \
            pk[0] = f2bf(xr[j].x); pk[1] = f2bf(xr[j].y);                      \
            pk[2] = f2bf(xr[j].z); pk[3] = f2bf(xr[j].w);                      \
            *(u16x4*)(xb_ + ((row * 128 + (tid & 15) * 8) ^ ((row & 7) << 4))) = pk; \
        }                                                                      \
    }

#define WSTAGE(kc_, nb_)                                                       \
    {                                                                          \
        u16* wl_ = smem + 32768 + (nb_) * 12288;                               \
        const u16* wg_ = Wf + (size_t)(kc_) * 12288;                           \
        _Pragma("unroll")                                                      \
        for (int p = 0; p < 3; ++p)                                            \
            gll16(wg_ + (p * 8 + w) * 512 + l * 8, wl_ + (p * 8 + w) * 512);   \
    }

#define COMPUTE(cur_)                                                          \
    {                                                                          \
        const char* xb = smB + (cur_) * 32768;                                 \
        const char* wb = smB + 65536 + (cur_) * 24576;                         \
        _Pragma("unroll")                                                      \
        for (int ksub = 0; ksub < 2; ++ksub) {                                 \
            short8 bfr[12], af[2];                                             \
            _Pragma("unroll")                                                  \
            for (int nt = 0; nt < 12; ++nt)                                    \
                bfr[nt] = *(const short8*)(wb + (ksub * 12 + nt) * 1024 + l * 16); \
            af[0] = *(const short8*)(xb +                                      \
                (((tt0 * 16 + lrow) * 128 + ksub * 64 + lgrp * 16) ^ cswz));   \
            af[1] = *(const short8*)(xb +                                      \
                (((tt1 * 16 + lrow) * 128 + ksub * 64 + lgrp * 16) ^ cswz));   \
            _Pragma("unroll")                                                  \
            for (int mrep = 0; mrep < 2; ++mrep)                               \
                _Pragma("unroll")                                              \
                for (int nt = 0; nt < 12; ++nt)                                \
                    acc[mrep][nt] = __builtin_amdgcn_mfma_f32_16x16x32_bf16(   \
                        af[mrep], bfr[nt], acc[mrep][nt], 0, 0, 0);            \
        }                                                                      \
    }

    // ---- Phase 1 ----
    XLOAD(0); WSTAGE(0, 0); XWRITE(0);
    __syncthreads();
    for (int kc = 0; kc < 12; ++kc) {
        const int cur = kc & 1;
        if (kc < 11) { WSTAGE(kc + 1, cur ^ 1); XLOAD(kc + 1); }
        COMPUTE(cur);
        if (kc < 11) { XWRITE(cur ^ 1); }
        __syncthreads();
    }
#undef XLOAD
#undef XWRITE
#undef WSTAGE
#undef COMPUTE

    // ---- Epilogue: acc -> KT / VT / QB ----
#pragma unroll
    for (int mrep = 0; mrep < 2; ++mrep) {
        const int tt = (mrep == 0) ? tt0 : tt1;
        const int s0 = tt * 16;
#pragma unroll
        for (int nt = 0; nt < 12; ++nt) {
            f32x4 a = acc[mrep][nt];
            if (nt < 4) {                       // Q -> QB [256][64]
                int h = nt * 16 + lrow;
#pragma unroll
                for (int r = 0; r < 4; ++r) {
                    int row = s0 + lgrp * 4 + r;
                    *(u16*)(smB + 65536 + ((row * 128 + h * 2) ^ ((row & 7) << 4))) = f2bf(a[r]);
                }
            } else if (nt < 8) {                // K -> KT [256][64]
                int h = (nt - 4) * 16 + lrow;
#pragma unroll
                for (int r = 0; r < 4; ++r) {
                    int s = s0 + lgrp * 4 + r;
                    *(u16*)(smB + ((s * 128 + h * 2) ^ ((s & 7) << 4))) = f2bf(a[r]);
                }
            } else {                            // V -> VT [64][256]
                int h = (nt - 8) * 16 + lrow;
                int s = s0 + lgrp * 4;
                u16x4 pk;
                pk[0] = f2bf(a[0]); pk[1] = f2bf(a[1]);
                pk[2] = f2bf(a[2]); pk[3] = f2bf(a[3]);
                *(u16x4*)(smB + 32768 + h * 512 + ((s * 2) ^ ((h & 15) << 4))) = pk;
            }
        }
    }
    __syncthreads();

    // Q fragment readback
    short8 qfr[2][2];
#pragma unroll
    for (int mt = 0; mt < 2; ++mt) {
        const int tt = (mt == 0) ? tt0 : tt1;
#pragma unroll
        for (int kk = 0; kk < 2; ++kk)
            qfr[mt][kk] = *(const short8*)(smB + 65536 +
                (((tt * 16 + lrow) * 128 + kk * 64 + lgrp * 16) ^ cswz));
    }

    // ---- Phase 2: causal attention (per-wave, no barriers) ----
    char* pbase = smB + 98304 + w * 2560;
#pragma unroll
    for (int mt = 0; mt < 2; ++mt) {
        const int tt = (mt == 0) ? tt0 : tt1;
        const int i0 = tt * 16;

        f32x4 sreg[16];
#pragma unroll
        for (int t = 0; t < 16; ++t) {
            if (t <= tt) {
                short8 k0 = *(const short8*)(smB +
                    (((t * 16 + lrow) * 128 + lgrp * 16) ^ cswz));
                short8 k1 = *(const short8*)(smB +
                    (((t * 16 + lrow) * 128 + 64 + lgrp * 16) ^ cswz));
                f32x4 s = (f32x4)0.f;
                s = __builtin_amdgcn_mfma_f32_16x16x32_bf16(qfr[mt][0], k0, s, 0, 0, 0);
                s = __builtin_amdgcn_mfma_f32_16x16x32_bf16(qfr[mt][1], k1, s, 0, 0, 0);
                if (t == tt) {
#pragma unroll
                    for (int r = 0; r < 4; ++r) {
                        int i = i0 + lgrp * 4 + r;
                        int sidx = t * 16 + lrow;
                        sreg[t][r] = (sidx <= i) ? s[r] * 0.125f : -1e30f;
                    }
                } else {
#pragma unroll
                    for (int r = 0; r < 4; ++r) sreg[t][r] = s[r] * 0.125f;
                }
            }
        }

        // row max
        f32x4 mx = (f32x4)(-1e30f);
#pragma unroll
        for (int t = 0; t < 16; ++t)
            if (t <= tt)
#pragma unroll
                for (int r = 0; r < 4; ++r) mx[r] = fmaxf(mx[r], sreg[t][r]);
#pragma unroll
        for (int m = 1; m <= 8; m <<= 1)
#pragma unroll
            for (int r = 0; r < 4; ++r) mx[r] = fmaxf(mx[r], __shfl_xor(mx[r], m, 64));

        // exp + sum
        f32x4 sm = (f32x4)0.f;
#pragma unroll
        for (int t = 0; t < 16; ++t)
            if (t <= tt)
#pragma unroll
                for (int r = 0; r < 4; ++r) {
                    float p = __expf(sreg[t][r] - mx[r]);
                    sreg[t][r] = p;
                    sm[r] += p;
                }
#pragma unroll
        for (int m = 1; m <= 8; m <<= 1)
#pragma unroll
            for (int r = 0; r < 4; ++r) sm[r] += __shfl_xor(sm[r], m, 64);

        float inv[4];
#pragma unroll
        for (int r = 0; r < 4; ++r) {
            int i = i0 + lgrp * 4 + r;
            inv[r] = (pad[b * Tt + i] != 0) ? (1.0f / sm[r]) : 0.0f;
        }

        // PV (chunked P through per-wave dbuf LDS)
        f32x4 o[4];
#pragma unroll
        for (int ht = 0; ht < 4; ++ht) o[ht] = (f32x4)0.f;
#pragma unroll
        for (int ks = 0; ks < 8; ++ks) {
            if (2 * ks <= tt) {
                char* pb = pbase + (ks & 1) * 1280;
#pragma unroll
                for (int r = 0; r < 4; ++r) {
                    int prow = lgrp * 4 + r;
                    *(u16*)(pb + prow * 80 + lrow * 2) = f2bf(sreg[2 * ks][r]);
                    u16 pv2 = (2 * ks + 1 <= tt) ? f2bf(sreg[2 * ks + 1][r]) : (u16)0;
                    *(u16*)(pb + prow * 80 + 32 + lrow * 2) = pv2;
                }
                short8 pa = *(const short8*)(pb + lrow * 80 + lgrp * 16);
#pragma unroll
                for (int ht = 0; ht < 4; ++ht) {
                    short8 vfr = *(const short8*)(smB + 32768 + (ht * 16 + lrow) * 512 +
                        ((ks * 64 + lgrp * 16) ^ (lrow << 4)));
                    o[ht] = __builtin_amdgcn_mfma_f32_16x16x32_bf16(pa, vfr, o[ht], 0, 0, 0);
                }
            }
        }

        // write out
        float* outp = out + ((size_t)b * Tt + i0) * Hh;
#pragma unroll
        for (int r = 0; r < 4; ++r)
#pragma unroll
            for (int ht = 0; ht < 4; ++ht)
                outp[(lgrp * 4 + r) * Hh + ht * 16 + lrow] = o[ht][r] * inv[r];
    }
}

// ---------------------------------------------------------------------------
extern "C" void kernel_launch(void* const* d_in, const int* in_sizes, int n_in,
                              void* d_out, int out_size, void* d_ws, size_t ws_size,
                              hipStream_t stream) {
    const float* x  = (const float*)d_in[0];
    const float* Wq = (const float*)d_in[1];
    const float* Wk = (const float*)d_in[2];
    const float* Wv = (const float*)d_in[3];
    const int* pad  = (const int*)d_in[4];
    float* out = (float*)d_out;

    u16* Wf = (u16*)d_ws;    // 294912 B

    wt_kernel<<<576, 256, 0, stream>>>(Wq, Wk, Wv, Wf);
    fused_kernel<<<Bb, 512, 0, stream>>>(x, Wf, pad, out);
}